// Round 5
// baseline (276.682 us; speedup 1.0000x reference)
//
#include <hip/hip_runtime.h>
#include <hip/hip_bf16.h>
#include <hip/hip_fp16.h>

// Problem constants (match reference)
constexpr int IMG_ = 256;
constexpr int M_   = 1920;   // N_SHOTS * N_SAMPLES
constexpr int B_   = 64;
constexpr int MI_  = M_ * IMG_;          // 491520 elements per phase table
constexpr int IMG2 = IMG_ * IMG_;        // 65536

typedef _Float16 half8 __attribute__((ext_vector_type(8)));
typedef float    floatx4 __attribute__((ext_vector_type(4)));

// global -> LDS direct copy, 16B per lane; LDS dest is wave-uniform base + lane*16
__device__ __forceinline__ void gll16(const _Float16* g, _Float16* l) {
  __builtin_amdgcn_global_load_lds(
      (const __attribute__((address_space(1))) void*)g,
      (__attribute__((address_space(3))) void*)l, 16, 0, 0);
}

// ---------------------------------------------------------------------------
// prep_k: fused {phase1 | phase2 | x-transpose} by blockIdx range (independent
// work; whole blocks take one branch). Saves 2 launches (~20 us of gaps).
// ---------------------------------------------------------------------------
constexpr int PH1_N = MI_ / 256;          // 1920
constexpr int PH2_N = 8 * IMG_;           // 2048
constexpr int XT_N  = 8 * 8 * B_;         // 4096

__global__ __launch_bounds__(256) void prep_k(
    const float* __restrict__ samples,
    const float* __restrict__ xr, const float* __restrict__ xi,
    _Float16* __restrict__ axh_r, _Float16* __restrict__ axh_i,
    _Float16* __restrict__ ayh_r, _Float16* __restrict__ ayh_i,
    _Float16* __restrict__ axtc_r, _Float16* __restrict__ axtc_i,
    _Float16* __restrict__ aytc_r, _Float16* __restrict__ aytc_i,
    _Float16* __restrict__ xth_r, _Float16* __restrict__ xth_i) {
  __shared__ float tr[32][33], ti[32][33];
  const int t = threadIdx.x;
  const int n = blockIdx.x;

  if (n < PH1_N) {
    // phase tables, natural layout [m][i]
    int idx = n * 256 + t;
    int m = idx >> 8;
    int i = idx & 255;
    float g  = (float)i - 128.0f;
    float kx = samples[2 * m + 0];
    float ky = samples[2 * m + 1];
    float sx, cx, sy, cy;
    sincospif(-2.0f * kx * g, &sx, &cx);
    sincospif(-2.0f * ky * g, &sy, &cy);
    axh_r[idx] = (_Float16)cx; axh_i[idx] = (_Float16)sx;
    ayh_r[idx] = (_Float16)cy; ayh_i[idx] = (_Float16)sy;
  } else if (n < PH1_N + PH2_N) {
    // transposed, pre-conjugated tables [i][m]
    int nn = n - PH1_N;
    int m = (nn & 7) * 256 + t;
    int i = nn >> 3;
    if (m < M_) {               // ROUND-4 BUG FIX: guard was dropped in fusion;
                                // m up to 2047 corrupted row i+1 of the tables.
      float g  = (float)i - 128.0f;
      float kx = samples[2 * m + 0];
      float ky = samples[2 * m + 1];
      float sx, cx, sy, cy;
      sincospif(-2.0f * kx * g, &sx, &cx);
      sincospif(-2.0f * ky * g, &sy, &cy);
      int o = i * M_ + m;
      axtc_r[o] = (_Float16)cx; axtc_i[o] = (_Float16)(-sx);
      aytc_r[o] = (_Float16)cy; aytc_i[o] = (_Float16)(-sy);
    }
  } else {
    // X transpose + f16 convert: xth[b][j][i] = x[b][i][j]
    int nn = n - PH1_N - PH2_N;
    const int b  = nn >> 6;
    const int i0 = (nn & 7) * 32, j0 = ((nn >> 3) & 7) * 32;
    const int r = t >> 5, c = t & 31;
#pragma unroll
    for (int k = 0; k < 4; ++k) {
      int row = r + k * 8;
      tr[row][c] = xr[(size_t)b * IMG2 + (i0 + row) * IMG_ + j0 + c];
      ti[row][c] = xi[(size_t)b * IMG2 + (i0 + row) * IMG_ + j0 + c];
    }
    __syncthreads();
#pragma unroll
    for (int k = 0; k < 4; ++k) {
      int row = r + k * 8;
      xth_r[(size_t)b * IMG2 + (j0 + row) * IMG_ + i0 + c] = (_Float16)tr[c][row];
      xth_i[(size_t)b * IMG2 + (j0 + row) * IMG_ + i0 + c] = (_Float16)ti[c][row];
    }
  }
}

// ---------------------------------------------------------------------------
// LDS swizzle (both GEMMs), per 32-half (64B) row of 4 16B chunks:
// physical chunk p of row r holds logical chunk p ^ ((r>>1)&3).
//  - staging via global_load_lds: HW writes lane-linear (lane l -> row l>>2,
//    phys chunk l&3); lane fetches global logical chunk (l&3)^((l>>3)&3).
//  - ds_read_b128 frags read phys chunk q ^ ((lr>>1)&3): zero bank conflicts
//    (measured rounds 1-3: SQ_LDS_BANK_CONFLICT = 0).
// ---------------------------------------------------------------------------

// ---------------------------------------------------------------------------
// Forward NDFT via f16 MFMA + fused Ay-weighted j-reduction + density.
//   kw[b,m] = density[m] * sum_j Ay[m,j] * (sum_i Ax[m,i] * X_b[i,j])
// Block: 256 thr = 4 waves; block tile 64m x 128j per jc, jc in {0,1} -> 16
// k-steps per block. Epilogue STREAMS per-mt (8 live f32, shfl-reduced,
// parked in scr LDS) -> no spill. Block writes final kw f16.
// Grid 1920 1-D, XCD-grouped: xcd = n&7, 30 consecutive blocks share b.
// ---------------------------------------------------------------------------
__global__ __launch_bounds__(256, 3) void fwd_k(
    const _Float16* __restrict__ axh_r, const _Float16* __restrict__ axh_i,
    const _Float16* __restrict__ ayh_r, const _Float16* __restrict__ ayh_i,
    const _Float16* __restrict__ xth_r, const _Float16* __restrict__ xth_i,
    const float* __restrict__ density,
    _Float16* __restrict__ kwh_r, _Float16* __restrict__ kwh_i) {
  __shared__ _Float16 lds[2][12288];   // 48 KB staging
  __shared__ float2 scr[4][64];        // 2 KB per-wave m-partials (separate!)

  const int t  = threadIdx.x;
  const int w  = t >> 6;
  const int l  = t & 63;
  const int lr = l & 15;   // frag row within 16-tile; C col (j)
  const int q  = l >> 4;   // k-chunk; C row group (m)

  const int n   = blockIdx.x;        // 0..1919
  const int xcd = n & 7;
  const int r   = n >> 3;            // 0..239
  const int b   = xcd + 8 * (r / 30);
  const int m0  = (r % 30) * 64;

  const int srow   = l >> 2;                      // staging row within 16
  const int schunk = (l & 3) ^ ((l >> 3) & 3);    // pre-swizzled global chunk
  const int gA     = srow * IMG_ + schunk * 8;    // halfs
  const int rc     = (q ^ ((lr >> 1) & 3)) << 3;  // frag-read swizzled chunk

  const floatx4 z4 = {0.f, 0.f, 0.f, 0.f};
  floatx4 accr[4][2], acci[4][2];
#pragma unroll
  for (int mt = 0; mt < 4; ++mt)
#pragma unroll
    for (int jt = 0; jt < 2; ++jt) { accr[mt][jt] = z4; acci[mt][jt] = z4; }

  auto stage = [&](int buf, int s) {
    const int jc  = s >> 3;
    const int col = (s & 7) * 32;
    _Float16* L = lds[buf];
    const size_t offA = (size_t)(m0 + w * 16) * IMG_ + col + gA;
    gll16(axh_r + offA, L + 0    + w * 512);
    gll16(axh_i + offA, L + 2048 + w * 512);
    const size_t offB = (size_t)b * IMG2 + (size_t)(jc * 128 + w * 32) * IMG_ + col + gA;
    gll16(xth_r + offB,             L + 4096 + w * 1024);
    gll16(xth_r + offB + 16 * IMG_, L + 4096 + w * 1024 + 512);
    gll16(xth_i + offB,             L + 8192 + w * 1024);
    gll16(xth_i + offB + 16 * IMG_, L + 8192 + w * 1024 + 512);
  };

  auto compute = [&](int buf) {
    const _Float16* L = lds[buf];
    half8 br[2], bi[2], nbi[2];
#pragma unroll
    for (int jt = 0; jt < 2; ++jt) {
      const int ro = (w * 32 + jt * 16 + lr) * 32 + rc;
      br[jt]  = *(const half8*)&L[4096 + ro];
      bi[jt]  = *(const half8*)&L[8192 + ro];
      nbi[jt] = -bi[jt];
    }
#pragma unroll
    for (int mt = 0; mt < 4; ++mt) {
      const int ro = (mt * 16 + lr) * 32 + rc;
      half8 ar = *(const half8*)&L[0 + ro];
      half8 ai = *(const half8*)&L[2048 + ro];
#pragma unroll
      for (int jt = 0; jt < 2; ++jt) {
        accr[mt][jt] = __builtin_amdgcn_mfma_f32_16x16x32_f16(ar, br[jt],  accr[mt][jt], 0, 0, 0);
        accr[mt][jt] = __builtin_amdgcn_mfma_f32_16x16x32_f16(ai, nbi[jt], accr[mt][jt], 0, 0, 0);
        acci[mt][jt] = __builtin_amdgcn_mfma_f32_16x16x32_f16(ar, bi[jt],  acci[mt][jt], 0, 0, 0);
        acci[mt][jt] = __builtin_amdgcn_mfma_f32_16x16x32_f16(ai, br[jt],  acci[mt][jt], 0, 0, 0);
      }
    }
  };

  // Streaming epilogue: per mt, fold Ay-weighted j-sum, shfl-reduce over the
  // 16 j-lanes, park in scr (per-wave slice). Only 8 f32 live at a time.
  auto epi = [&](int jc) {
#pragma unroll
    for (int mt = 0; mt < 4; ++mt) {
      float kr[4] = {}, ki[4] = {};
#pragma unroll
      for (int jt = 0; jt < 2; ++jt) {
        const int j = jc * 128 + w * 32 + jt * 16 + lr;
#pragma unroll
        for (int reg = 0; reg < 4; ++reg) {
          const int m = m0 + mt * 16 + q * 4 + reg;
          const float yr = (float)ayh_r[m * IMG_ + j];
          const float yi = (float)ayh_i[m * IMG_ + j];
          const float tr = accr[mt][jt][reg], ti = acci[mt][jt][reg];
          kr[reg] = fmaf(yr, tr, fmaf(-yi, ti, kr[reg]));
          ki[reg] = fmaf(yr, ti, fmaf(yi, tr, ki[reg]));
        }
        accr[mt][jt] = z4;
        acci[mt][jt] = z4;
      }
#pragma unroll
      for (int reg = 0; reg < 4; ++reg)
#pragma unroll
        for (int off = 1; off < 16; off <<= 1) {
          kr[reg] += __shfl_xor(kr[reg], off);
          ki[reg] += __shfl_xor(ki[reg], off);
        }
      if (lr == 0) {
#pragma unroll
        for (int reg = 0; reg < 4; ++reg) {
          const int ml = mt * 16 + q * 4 + reg;
          if (jc == 0) {
            scr[w][ml] = make_float2(kr[reg], ki[reg]);
          } else {
            float2 p = scr[w][ml];
            scr[w][ml] = make_float2(p.x + kr[reg], p.y + ki[reg]);
          }
        }
      }
    }
  };

  stage(0, 0);
  __syncthreads();               // implicit vmcnt(0) drains global_load_lds
#pragma unroll
  for (int s = 0; s < 16; ++s) {
    const int buf = s & 1;
    if (s < 15) stage(buf ^ 1, s + 1);    // next-tile loads overlap MFMA
    compute(buf);
    if (s == 7) epi(0);                   // overlaps in-flight stage(8) loads
    __syncthreads();
  }
  epi(1);
  __syncthreads();

  // cross-wave combine (4 j-slices), density, final f16 kw write
  if (t < 64) {
    float sr = 0.f, si = 0.f;
#pragma unroll
    for (int ww = 0; ww < 4; ++ww) {
      const float2 p = scr[ww][t];
      sr += p.x; si += p.y;
    }
    const int m = m0 + t;
    const float d = density[m];
    kwh_r[b * M_ + m] = (_Float16)(sr * d);
    kwh_i[b * M_ + m] = (_Float16)(si * d);
  }
}

// ---------------------------------------------------------------------------
// Adjoint NDFT via f16 MFMA:
//   out[b,i,j] = (1/IMG^2) sum_m conj(Ax)[m,i] * kw[b,m] * conj(Ay)[m,j]
// Block tile 64i x 64j, 4 waves of 32x32 (acc 64), LDS 32 KB -> 3 blocks/CU
// = 12 waves/CU. K = 1920, 60 double-buffered steps.
// Grid 1024 1-D, XCD-grouped: xcd = n&7 owns 2 (i0,j0) combos x 64 b ->
// axtc/aytc strips (~1 MB) L2-resident per XCD.
// ---------------------------------------------------------------------------
__global__ __launch_bounds__(256, 3) void adj_k(
    const _Float16* __restrict__ axtc_r, const _Float16* __restrict__ axtc_i,
    const _Float16* __restrict__ aytc_r, const _Float16* __restrict__ aytc_i,
    const _Float16* __restrict__ kwh_r, const _Float16* __restrict__ kwh_i,
    float* __restrict__ out) {
  __shared__ _Float16 lds[2][8192];    // 32 KB: {A_r,A_i,W_r,W_i} x dbuf

  const int t  = threadIdx.x;
  const int w  = t >> 6;
  const int l  = t & 63;
  const int lr = l & 15;
  const int q  = l >> 4;
  const int wi = w >> 1;               // 2 wave-rows (i)
  const int wj = w & 1;                // 2 wave-cols (j)

  const int n     = blockIdx.x;        // 0..1023
  const int xcd   = n & 7;
  const int r     = n >> 3;            // 0..127
  const int combo = xcd + 8 * (r >> 6);  // 0..15
  const int b     = r & 63;
  const int i0    = (combo >> 2) * 64;
  const int j0    = (combo & 3) * 64;

  const int srow   = l >> 2;
  const int schunk = (l & 3) ^ ((l >> 3) & 3);
  const int gA     = srow * M_ + schunk * 8;      // A row stride = 1920 halfs
  const int rc     = (q ^ ((lr >> 1) & 3)) << 3;

  // W staging: thread -> (j-row = t>>2, 8-half seg = t&3); swizzled b128 write
  const int wrow = t >> 2;
  const int wseg = t & 3;
  const int wsc  = wseg ^ ((wrow >> 1) & 3);      // logical (global) chunk

  const floatx4 z4 = {0.f, 0.f, 0.f, 0.f};
  floatx4 accr[2][2], acci[2][2];
#pragma unroll
  for (int mt = 0; mt < 2; ++mt)
#pragma unroll
    for (int jt = 0; jt < 2; ++jt) { accr[mt][jt] = z4; acci[mt][jt] = z4; }

  uint4 Yr, Yi, Cr, Ci;

  auto stageA = [&](int buf, int s) {
    const int mc = s * 32;
    _Float16* L = lds[buf];
    const size_t off = (size_t)(i0 + w * 16) * M_ + mc + gA;
    gll16(axtc_r + off, L + 0    + w * 512);
    gll16(axtc_i + off, L + 2048 + w * 512);
  };

  auto loadW = [&](int s) {   // issue early; consumed by writeW after compute
    const int mc = s * 32 + wsc * 8;
    const size_t oy = (size_t)(j0 + wrow) * M_ + mc;
    const size_t oc = (size_t)b * M_ + mc;
    Yr = *(const uint4*)&aytc_r[oy];
    Yi = *(const uint4*)&aytc_i[oy];
    Cr = *(const uint4*)&kwh_r[oc];
    Ci = *(const uint4*)&kwh_i[oc];
  };

  auto writeW = [&](int buf) {
    __half2 Wr[4], Wi2[4];
    const __half2* yr = (const __half2*)&Yr; const __half2* yi = (const __half2*)&Yi;
    const __half2* cr = (const __half2*)&Cr; const __half2* ci = (const __half2*)&Ci;
#pragma unroll
    for (int e = 0; e < 4; ++e) {
      Wr[e]  = __hsub2(__hmul2(cr[e], yr[e]), __hmul2(ci[e], yi[e]));
      Wi2[e] = __hfma2(cr[e], yi[e], __hmul2(ci[e], yr[e]));
    }
    _Float16* Lr = lds[buf] + 4096;
    _Float16* Li = lds[buf] + 6144;
    const int o = wrow * 32 + wseg * 8;
    *(uint4*)&Lr[o] = *(const uint4*)&Wr[0];
    *(uint4*)&Li[o] = *(const uint4*)&Wi2[0];
  };

  auto compute = [&](int buf) {
    const _Float16* L = lds[buf];
    half8 br[2], bi[2], nbi[2];
#pragma unroll
    for (int jt = 0; jt < 2; ++jt) {
      const int ro = (wj * 32 + jt * 16 + lr) * 32 + rc;
      br[jt]  = *(const half8*)&L[4096 + ro];
      bi[jt]  = *(const half8*)&L[6144 + ro];
      nbi[jt] = -bi[jt];
    }
#pragma unroll
    for (int mt = 0; mt < 2; ++mt) {
      const int ro = (wi * 32 + mt * 16 + lr) * 32 + rc;
      half8 ar = *(const half8*)&L[0 + ro];
      half8 ai = *(const half8*)&L[2048 + ro];
#pragma unroll
      for (int jt = 0; jt < 2; ++jt) {
        accr[mt][jt] = __builtin_amdgcn_mfma_f32_16x16x32_f16(ar, br[jt],  accr[mt][jt], 0, 0, 0);
        accr[mt][jt] = __builtin_amdgcn_mfma_f32_16x16x32_f16(ai, nbi[jt], accr[mt][jt], 0, 0, 0);
        acci[mt][jt] = __builtin_amdgcn_mfma_f32_16x16x32_f16(ar, bi[jt],  acci[mt][jt], 0, 0, 0);
        acci[mt][jt] = __builtin_amdgcn_mfma_f32_16x16x32_f16(ai, br[jt],  acci[mt][jt], 0, 0, 0);
      }
    }
  };

  loadW(0);
  stageA(0, 0);
  writeW(0);
  __syncthreads();
#pragma unroll 2
  for (int s = 0; s < 60; ++s) {
    const int buf = s & 1;
    if (s < 59) { stageA(buf ^ 1, s + 1); loadW(s + 1); }
    compute(buf);
    if (s < 59) writeW(buf ^ 1);
    __syncthreads();
  }

  const float sc = 1.0f / (float)IMG2;
#pragma unroll
  for (int mt = 0; mt < 2; ++mt)
#pragma unroll
    for (int jt = 0; jt < 2; ++jt) {
      const int jg = j0 + wj * 32 + jt * 16 + lr;
#pragma unroll
      for (int reg = 0; reg < 4; ++reg) {
        const int ig = i0 + wi * 32 + mt * 16 + q * 4 + reg;
        float2 v = make_float2(accr[mt][jt][reg] * sc, acci[mt][jt][reg] * sc);
        *(float2*)&out[((size_t)(b * IMG_ + ig) * IMG_ + jg) * 2] = v;
      }
    }
}

// ---------------------------------------------------------------------------
// Launch: 3 kernels (was 6) -> less launch-gap overhead.
// ---------------------------------------------------------------------------
extern "C" void kernel_launch(void* const* d_in, const int* in_sizes, int n_in,
                              void* d_out, int out_size, void* d_ws, size_t ws_size,
                              hipStream_t stream) {
  (void)in_sizes; (void)n_in; (void)out_size; (void)ws_size;

  const float* xr      = (const float*)d_in[0];
  const float* xi      = (const float*)d_in[1];
  const float* samples = (const float*)d_in[2];
  const float* density = (const float*)d_in[3];
  float* out = (float*)d_out;

  // ws: 10 f16 arrays, 8.36 MB total
  _Float16* f = (_Float16*)d_ws;
  _Float16* axh_r  = f + 0 * MI_;
  _Float16* axh_i  = f + 1 * MI_;
  _Float16* ayh_r  = f + 2 * MI_;
  _Float16* ayh_i  = f + 3 * MI_;
  _Float16* axtc_r = f + 4 * MI_;
  _Float16* axtc_i = f + 5 * MI_;
  _Float16* aytc_r = f + 6 * MI_;
  _Float16* aytc_i = f + 7 * MI_;
  _Float16* kwh_r  = f + 8 * MI_;
  _Float16* kwh_i  = kwh_r + B_ * M_;

  // X^T (f16) parked in d_out; fully consumed by fwd_k before adj_k overwrites.
  _Float16* xth_r = (_Float16*)d_out;
  _Float16* xth_i = xth_r + (size_t)B_ * IMG2;

  prep_k<<<PH1_N + PH2_N + XT_N, 256, 0, stream>>>(
      samples, xr, xi, axh_r, axh_i, ayh_r, ayh_i,
      axtc_r, axtc_i, aytc_r, aytc_i, xth_r, xth_i);
  fwd_k<<<1920, 256, 0, stream>>>(axh_r, axh_i, ayh_r, ayh_i,
                                  xth_r, xth_i, density, kwh_r, kwh_i);
  adj_k<<<1024, 256, 0, stream>>>(axtc_r, axtc_i, aytc_r, aytc_i,
                                  kwh_r, kwh_i, out);
}